// Round 8
// baseline (261.832 us; speedup 1.0000x reference)
//
#include <hip/hip_runtime.h>

// GraphSAGE 2-layer + classifier on MI355X.
// Round 8: XCD-local degree histograms (8 replicas, s_getreg(HW_REG_XCC_ID))
// to eliminate cross-XCD atomic line migration; rank packs (xcd<<28)|r;
// scan1 emits per-node per-XCD exclusive prefix (ushort).
// N=100000, E=1600000, C=HID=64.
//
// ws: offs(N+1) | bsum(nb) | {deg_rep(8N int) -> csr(E)} |
//     h1(N*64 fp16; rank(E int) at +0, xcdpref(8N ushort) at +E*4, both die
//     before sage1) | xh(N*64 fp16) | wp(32KB)   total ~32.5 MB

#define C 64

typedef _Float16 half8 __attribute__((ext_vector_type(8)));
typedef float f32x4 __attribute__((ext_vector_type(4)));

static inline size_t align256(size_t x) { return (x + 255) & ~(size_t)255; }

__device__ inline int xcc_id() {
    unsigned x;
    asm("s_getreg_b32 %0, hwreg(HW_REG_XCC_ID)" : "=s"(x));
    return (int)(x & 7u);
}

// ---------------- prep: count+rank | cvt x->fp16 | pack weights ----------------
__device__ void count_part(const int* __restrict__ ei, int* __restrict__ deg_rep,
                           int* __restrict__ rank, int E, int n, int bid) {
    int i = bid * 256 + (int)threadIdx.x;
    int nE4 = E >> 2;
    const int xcd = xcc_id();                   // wave-uniform
    int* drep = deg_rep + (size_t)xcd * n;      // this XCD's private replica
    const int tag = xcd << 28;
    if (i < nE4) {
        int4 d = ((const int4*)(ei + E))[i];    // row 1 = dst
        int4 r;
        r.x = atomicAdd(&drep[d.x], 1) | tag;   // XCD-local line: no migration
        r.y = atomicAdd(&drep[d.y], 1) | tag;
        r.z = atomicAdd(&drep[d.z], 1) | tag;
        r.w = atomicAdd(&drep[d.w], 1) | tag;
        ((int4*)rank)[i] = r;                   // coalesced
    }
    if (bid == 0 && threadIdx.x == 0) {
        for (int e = nE4 << 2; e < E; ++e)
            rank[e] = atomicAdd(&drep[ei[E + e]], 1) | tag;
    }
}

__device__ void cvt_part(const float* __restrict__ x, _Float16* __restrict__ xh,
                         int n8, int bid) {
    int i = bid * 256 + (int)threadIdx.x;
    if (i < n8) {
        const float4* p = (const float4*)x + (size_t)i * 2;
        float4 a = p[0], b = p[1];
        half8 h;
        h[0] = (_Float16)a.x; h[1] = (_Float16)a.y; h[2] = (_Float16)a.z; h[3] = (_Float16)a.w;
        h[4] = (_Float16)b.x; h[5] = (_Float16)b.y; h[6] = (_Float16)b.z; h[7] = (_Float16)b.w;
        ((half8*)xh)[i] = h;
    }
}

// wp[mat][tile(4)][step(2)][lane(64)][j(8)], B[k][n]: k = step*32+(lane>>4)*8+j,
// n = tile*16 + (lane&15).
__device__ void wpack_part(const float* __restrict__ W0, const float* __restrict__ W1,
                           const float* __restrict__ W2, const float* __restrict__ W3,
                           _Float16* __restrict__ wp, int bid) {
    int t = bid * 256 + (int)threadIdx.x;
    if (t >= 2048) return;
    int lane = t & 63, step = (t >> 6) & 1, tile = (t >> 7) & 3, mat = t >> 9;
    const float* W = (mat == 0) ? W0 : (mat == 1) ? W1 : (mat == 2) ? W2 : W3;
    int col = tile * 16 + (lane & 15);
    int k0  = step * 32 + ((lane >> 4) << 3);
    half8 h;
    #pragma unroll
    for (int j = 0; j < 8; ++j) h[j] = (_Float16)W[(k0 + j) * C + col];
    ((half8*)wp)[t] = h;
}

__global__ __launch_bounds__(256) void prep_kernel(
    const int* __restrict__ ei, int* __restrict__ deg_rep, int* __restrict__ rank,
    int E, int n,
    const float* __restrict__ x, _Float16* __restrict__ xh, int n8,
    const float* __restrict__ W0, const float* __restrict__ W1,
    const float* __restrict__ W2, const float* __restrict__ W3,
    _Float16* __restrict__ wp, int egrid, int cgrid)
{
    int bid = blockIdx.x;
    if (bid < egrid)              count_part(ei, deg_rep, rank, E, n, bid);
    else if (bid < egrid + cgrid) cvt_part(x, xh, n8, bid - egrid);
    else                          wpack_part(W0, W1, W2, W3, wp, bid - egrid - cgrid);
}

// ---------------- scan: sum 8 replicas, emit xcd-prefix + block scan ----------------
__global__ __launch_bounds__(1024) void scan1_kernel(const int* __restrict__ deg_rep,
                                                     int* __restrict__ offs,
                                                     int* __restrict__ bsum,
                                                     unsigned short* __restrict__ xcdpref,
                                                     int n) {
    __shared__ int wsum[16];
    const int lane = threadIdx.x & 63;
    const int wid  = threadIdx.x >> 6;
    int i = blockIdx.x * 1024 + threadIdx.x;
    int v = 0;
    if (i < n) {
        union { unsigned short u[8]; uint4 q; } P;
        int tot = 0;
        #pragma unroll
        for (int xx = 0; xx < 8; ++xx) {
            int c = deg_rep[(size_t)xx * n + i];
            P.u[xx] = (unsigned short)tot;   // exclusive prefix (deg <= 65535)
            tot += c;
        }
        ((uint4*)xcdpref)[i] = P.q;
        v = tot;
    }
    int s = v;
    #pragma unroll
    for (int off = 1; off < 64; off <<= 1) {
        int t = __shfl_up(s, off, 64);
        if (lane >= off) s += t;
    }
    if (lane == 63) wsum[wid] = s;
    __syncthreads();
    int wprefix = 0;
    for (int w = 0; w < wid; ++w) wprefix += wsum[w];
    if (i < n) offs[i] = wprefix + (s - v);
    if (threadIdx.x == 0) {
        int tot = 0;
        #pragma unroll
        for (int w = 0; w < 16; ++w) tot += wsum[w];
        bsum[blockIdx.x] = tot;
    }
}

__global__ __launch_bounds__(1024) void scan2_kernel(int* __restrict__ bsum,
                                                     int* __restrict__ offs, int nb, int n) {
    __shared__ int wsum[16];
    const int lane = threadIdx.x & 63;
    const int wid  = threadIdx.x >> 6;
    int v = ((int)threadIdx.x < nb) ? bsum[threadIdx.x] : 0;
    int s = v;
    #pragma unroll
    for (int off = 1; off < 64; off <<= 1) {
        int t = __shfl_up(s, off, 64);
        if (lane >= off) s += t;
    }
    if (lane == 63) wsum[wid] = s;
    __syncthreads();
    int wprefix = 0;
    for (int w = 0; w < wid; ++w) wprefix += wsum[w];
    if ((int)threadIdx.x < nb) bsum[threadIdx.x] = wprefix + (s - v);
    if (threadIdx.x == 0) {
        int tot = 0;
        #pragma unroll
        for (int w = 0; w < 16; ++w) tot += wsum[w];
        offs[n] = tot;   // grand total (bsum already folded in)
    }
}

// ---------------- fill (no atomics; xcd-prefix + bsum applied on the fly) ----------------
__global__ __launch_bounds__(256) void fill_kernel(
    const int* __restrict__ ei, const int* __restrict__ offs,
    const int* __restrict__ bsum, const unsigned short* __restrict__ xcdpref,
    const int* __restrict__ rank, int* __restrict__ csr, int E)
{
    int i = blockIdx.x * 256 + (int)threadIdx.x;
    int nE4 = E >> 2;
    if (i < nE4) {
        int4 s = ((const int4*)ei)[i];
        int4 d = ((const int4*)(ei + E))[i];
        int4 r = ((const int4*)rank)[i];
        int o0 = offs[d.x] + bsum[d.x >> 10]
               + xcdpref[(size_t)d.x * 8 + (((unsigned)r.x) >> 28)] + (r.x & 0x0FFFFFFF);
        int o1 = offs[d.y] + bsum[d.y >> 10]
               + xcdpref[(size_t)d.y * 8 + (((unsigned)r.y) >> 28)] + (r.y & 0x0FFFFFFF);
        int o2 = offs[d.z] + bsum[d.z >> 10]
               + xcdpref[(size_t)d.z * 8 + (((unsigned)r.z) >> 28)] + (r.z & 0x0FFFFFFF);
        int o3 = offs[d.w] + bsum[d.w >> 10]
               + xcdpref[(size_t)d.w * 8 + (((unsigned)r.w) >> 28)] + (r.w & 0x0FFFFFFF);
        csr[o0] = s.x;
        csr[o1] = s.y;
        csr[o2] = s.z;
        csr[o3] = s.w;
    }
    if (blockIdx.x == 0 && threadIdx.x == 0) {
        for (int e = nE4 << 2; e < E; ++e) {
            int d = ei[E + e];
            int rp = rank[e];
            csr[offs[d] + bsum[d >> 10]
                + xcdpref[(size_t)d * 8 + (((unsigned)rp) >> 28)] + (rp & 0x0FFFFFFF)] = ei[e];
        }
    }
}

// ---------------- fused SAGE layer ----------------
// Block = 256 = 4 waves = 32 nodes. Gather: lane = (slot<<3)|sub, slot=node,
// sub=16B chunk; each lane owns (node, 8ch) f32 acc. 4-deep row ILP.
// MLP: h = relu(agg @ Wl + bl + x @ Wr) via mfma_f32_16x16x32_f16.
template <bool FINAL>
__global__ __launch_bounds__(256) void sage_kernel(
    const _Float16* __restrict__ Xh, const int* __restrict__ csr,
    const int* __restrict__ offs, const int* __restrict__ bsum,
    const _Float16* __restrict__ wpL, const _Float16* __restrict__ wpR,
    const float* __restrict__ bl,
    const float* __restrict__ Wc, const float* __restrict__ bc,
    void* __restrict__ outp, int n)
{
    const int lane = threadIdx.x & 63;
    const int wid  = threadIdx.x >> 6;
    const int base = blockIdx.x * 32;
    __shared__ _Float16 Aagg[32][72];
    __shared__ float Opart[2][2][16];

    // ---- gather ----
    const int slot = lane >> 3;
    const int sub  = lane & 7;
    const int node = base + wid * 8 + slot;
    float acc[8] = {0.f,0.f,0.f,0.f,0.f,0.f,0.f,0.f};
    int dcount = 0;
    if (node < n) {
        int start = offs[node] + bsum[node >> 10];
        int end   = (node + 1 == n) ? offs[n]
                                    : offs[node + 1] + bsum[(node + 1) >> 10];
        dcount = end - start;
        int k = 0;
        for (; k + 4 <= dcount; k += 4) {
            int i0 = csr[start + k + 0];
            int i1 = csr[start + k + 1];
            int i2 = csr[start + k + 2];
            int i3 = csr[start + k + 3];
            half8 v0 = *(const half8*)(Xh + ((size_t)i0 << 6) + (sub << 3));
            half8 v1 = *(const half8*)(Xh + ((size_t)i1 << 6) + (sub << 3));
            half8 v2 = *(const half8*)(Xh + ((size_t)i2 << 6) + (sub << 3));
            half8 v3 = *(const half8*)(Xh + ((size_t)i3 << 6) + (sub << 3));
            #pragma unroll
            for (int j = 0; j < 8; ++j) acc[j] += (float)v0[j];
            #pragma unroll
            for (int j = 0; j < 8; ++j) acc[j] += (float)v1[j];
            #pragma unroll
            for (int j = 0; j < 8; ++j) acc[j] += (float)v2[j];
            #pragma unroll
            for (int j = 0; j < 8; ++j) acc[j] += (float)v3[j];
        }
        for (; k < dcount; ++k) {
            int i0 = csr[start + k];
            half8 v0 = *(const half8*)(Xh + ((size_t)i0 << 6) + (sub << 3));
            #pragma unroll
            for (int j = 0; j < 8; ++j) acc[j] += (float)v0[j];
        }
    }
    float inv = 1.0f / fmaxf((float)dcount, 1.0f);
    half8 hv;
    #pragma unroll
    for (int j = 0; j < 8; ++j) hv[j] = (_Float16)(acc[j] * inv);
    *(half8*)&Aagg[wid * 8 + slot][sub * 8] = hv;
    __syncthreads();

    // ---- MFMA MLP ----
    const int Mtile = wid >> 1;
    const int pair  = wid & 1;
    const int row16 = lane & 15;
    const int kg    = lane >> 4;
    const int myrow = base + Mtile * 16 + row16;
    const int srow  = (myrow < n) ? myrow : 0;

    half8 ag0 = *(const half8*)&Aagg[Mtile * 16 + row16][kg * 8];
    half8 ag1 = *(const half8*)&Aagg[Mtile * 16 + row16][32 + kg * 8];
    const _Float16* xrow = Xh + ((size_t)srow << 6);
    half8 xi0 = *(const half8*)(xrow + kg * 8);
    half8 xi1 = *(const half8*)(xrow + 32 + kg * 8);

    float ptot[4] = {0.f, 0.f, 0.f, 0.f};
    #pragma unroll
    for (int q = 0; q < 2; ++q) {
        const int ct = pair * 2 + q;
        const half8* BL = (const half8*)(wpL + (size_t)ct * 1024);
        const half8* BR = (const half8*)(wpR + (size_t)ct * 1024);
        half8 b0 = BL[lane];
        half8 b1 = BL[64 + lane];
        half8 b2 = BR[lane];
        half8 b3 = BR[64 + lane];
        f32x4 cacc = {0.f, 0.f, 0.f, 0.f};
        cacc = __builtin_amdgcn_mfma_f32_16x16x32_f16(ag0, b0, cacc, 0, 0, 0);
        cacc = __builtin_amdgcn_mfma_f32_16x16x32_f16(ag1, b1, cacc, 0, 0, 0);
        cacc = __builtin_amdgcn_mfma_f32_16x16x32_f16(xi0, b2, cacc, 0, 0, 0);
        cacc = __builtin_amdgcn_mfma_f32_16x16x32_f16(xi1, b3, cacc, 0, 0, 0);

        const int col = ct * 16 + row16;
        const float bias = bl[col];
        if (!FINAL) {
            _Float16* h1 = (_Float16*)outp;
            #pragma unroll
            for (int j = 0; j < 4; ++j) {
                int r = base + Mtile * 16 + kg * 4 + j;
                if (r < n) {
                    float v = fmaxf(cacc[j] + bias, 0.f);
                    h1[((size_t)r << 6) + col] = (_Float16)v;
                }
            }
        } else {
            const float wc = Wc[col];
            float p[4];
            #pragma unroll
            for (int j = 0; j < 4; ++j) p[j] = fmaxf(cacc[j] + bias, 0.f) * wc;
            #pragma unroll
            for (int off = 1; off < 16; off <<= 1) {
                #pragma unroll
                for (int j = 0; j < 4; ++j) p[j] += __shfl_xor(p[j], off, 64);
            }
            #pragma unroll
            for (int j = 0; j < 4; ++j) ptot[j] += p[j];
        }
    }

    if (FINAL) {
        if (row16 == 0) {
            #pragma unroll
            for (int j = 0; j < 4; ++j) Opart[Mtile][pair][kg * 4 + j] = ptot[j];
        }
        __syncthreads();
        const int tid = threadIdx.x;
        if (tid < 32) {
            int Mt = tid >> 4, r = tid & 15;
            int gr = base + Mt * 16 + r;
            if (gr < n)
                ((float*)outp)[gr] = Opart[Mt][0][r] + Opart[Mt][1][r] + bc[0];
        }
    }
}

extern "C" void kernel_launch(void* const* d_in, const int* in_sizes, int n_in,
                              void* d_out, int out_size, void* d_ws, size_t ws_size,
                              hipStream_t stream) {
    const float* x   = (const float*)d_in[0];
    const int*   ei  = (const int*)d_in[1];
    const float* Wl1 = (const float*)d_in[2];
    const float* bl1 = (const float*)d_in[3];
    const float* Wr1 = (const float*)d_in[4];
    const float* Wl2 = (const float*)d_in[5];
    const float* bl2 = (const float*)d_in[6];
    const float* Wr2 = (const float*)d_in[7];
    const float* Wc  = (const float*)d_in[8];
    const float* bc  = (const float*)d_in[9];
    float* out = (float*)d_out;

    const int N = in_sizes[0] / C;
    const int E = in_sizes[1] / 2;
    const int nb = (N + 1023) / 1024;

    char* ws = (char*)d_ws;
    size_t off = 0;
    int* offs = (int*)(ws + off); off += align256((size_t)(N + 1) * 4);
    int* bsum = (int*)(ws + off); off += align256((size_t)nb * 4);
    // deg_rep (8N ints) and csr (E ints) share a region (deg_rep dies after
    // scan1; csr written by fill afterwards).
    size_t shared_sz = (size_t)E * 4 > (size_t)N * 32 ? (size_t)E * 4 : (size_t)N * 32;
    int* csr = (int*)(ws + off);
    int* deg_rep = csr; off += align256(shared_sz);
    _Float16* h1 = (_Float16*)(ws + off); off += align256((size_t)N * C * 2);
    _Float16* xh = (_Float16*)(ws + off); off += align256((size_t)N * C * 2);
    _Float16* wp = (_Float16*)(ws + off); off += align256((size_t)2048 * 8 * 2);
    if (off > ws_size) return;   // fail loudly rather than corrupt neighbors

    // rank + xcdpref alias h1 (both die before sage1 writes h1)
    int* rank = (int*)h1;
    unsigned short* xcdpref = (unsigned short*)((char*)h1 + (size_t)E * 4);

    const int blk = 256;
    const int egrid = (E / 4 + blk - 1) / blk;       // count blocks (int4/thread)
    const int n8 = N * C / 8;
    const int cgrid = (n8 + blk - 1) / blk;          // cvt blocks
    hipMemsetAsync(deg_rep, 0, (size_t)N * 32, stream);
    prep_kernel<<<egrid + cgrid + 8, blk, 0, stream>>>(
        ei, deg_rep, rank, E, N, x, xh, n8, Wl1, Wr1, Wl2, Wr2, wp, egrid, cgrid);
    scan1_kernel<<<nb, 1024, 0, stream>>>(deg_rep, offs, bsum, xcdpref, N);
    scan2_kernel<<<1, 1024, 0, stream>>>(bsum, offs, nb, N);
    fill_kernel<<<egrid, blk, 0, stream>>>(ei, offs, bsum, xcdpref, rank, csr, E);

    const int node_grid = (N + 31) / 32;
    sage_kernel<false><<<node_grid, blk, 0, stream>>>(
        xh, csr, offs, bsum, wp, wp + 4096, bl1, nullptr, nullptr, h1, N);
    sage_kernel<true><<<node_grid, blk, 0, stream>>>(
        h1, csr, offs, bsum, wp + 8192, wp + 12288, bl2, Wc, bc, out, N);
}